// Round 2
// baseline (417.969 us; speedup 1.0000x reference)
//
#include <hip/hip_runtime.h>

typedef _Float16 f16x8 __attribute__((ext_vector_type(8)));
typedef _Float16 f16x4 __attribute__((ext_vector_type(4)));
typedef float    f32x4 __attribute__((ext_vector_type(4)));

#define GAMMA_F 0.00390625f

// ---------------------------------------------------------------------------
// prep: fp32 -> fp16 row conversion + row sum-of-squares (for x and sv)
// one wave per 256-element row
// ---------------------------------------------------------------------------
__global__ __launch_bounds__(256) void prep_rows_kernel(
    const float* __restrict__ src, _Float16* __restrict__ dst,
    float* __restrict__ sq, int nrows)
{
    int lane = threadIdx.x & 63, w = threadIdx.x >> 6;
    int row = blockIdx.x * 4 + w;
    if (row >= nrows) return;
    float4 v = ((const float4*)(src + (size_t)row * 256))[lane];
    f16x4 h;
    h[0] = (_Float16)v.x; h[1] = (_Float16)v.y;
    h[2] = (_Float16)v.z; h[3] = (_Float16)v.w;
    *((f16x4*)(dst + (size_t)row * 256) + lane) = h;
    float ss = v.x*v.x + v.y*v.y + v.z*v.z + v.w*v.w;
#pragma unroll
    for (int off = 32; off; off >>= 1) ss += __shfl_down(ss, off);
    if (lane == 0) sq[row] = ss;
}

// ---------------------------------------------------------------------------
// prep: plain fp32 -> fp16 conversion (weights), float4 granularity
// ---------------------------------------------------------------------------
__global__ __launch_bounds__(256) void cvt_kernel(
    const float* __restrict__ src, _Float16* __restrict__ dst, int n4)
{
    int i = blockIdx.x * 256 + threadIdx.x;
    if (i < n4) {
        float4 v = ((const float4*)src)[i];
        f16x4 h;
        h[0] = (_Float16)v.x; h[1] = (_Float16)v.y;
        h[2] = (_Float16)v.z; h[3] = (_Float16)v.w;
        ((f16x4*)dst)[i] = h;
    }
}

// ---------------------------------------------------------------------------
// GEMM: C[m][n] = epilogue( sum_k A[m][k] * B[n][k] )
//   A: M x K fp16 row-major, B: 1024 x K fp16 row-major ("bs,os->bo" form)
//   MODE 0: C = exp(-gamma*(x2[m] + s2[n] - 2*acc))   (e0=x2, e1=s2)
//   MODE 1: C = relu(acc + bias[n])                   (e0=bias)
// 128x128 tile, BK=64, 4 waves, mfma_f32_16x16x32_f16, global_load_lds w=16,
// st_16x32-style XOR swizzle via pre-swizzled global source (rule #21).
// grid = (M/128)*8 blocks, XCD-bijective swizzle (grid % 8 == 0 always).
// ---------------------------------------------------------------------------
__device__ __forceinline__ void stage_pair(
    const _Float16* __restrict__ A, const _Float16* __restrict__ B,
    int rowA0, int rowB0, int k0, int ld, int t,
    f16x8* Abuf, f16x8* Bbuf)
{
#pragma unroll
    for (int i = 0; i < 4; ++i) {
        int p   = i * 256 + t;           // linear 16B chunk id in LDS
        int row = p >> 3;
        int cg  = (p & 7) ^ (row & 7);   // inverse-swizzled global col-group
        const _Float16* ga = A + (size_t)(rowA0 + row) * ld + k0 + cg * 8;
        __builtin_amdgcn_global_load_lds(
            (const __attribute__((address_space(1))) void*)ga,
            (__attribute__((address_space(3))) void*)(Abuf + p), 16, 0, 0);
        const _Float16* gb = B + (size_t)(rowB0 + row) * ld + k0 + cg * 8;
        __builtin_amdgcn_global_load_lds(
            (const __attribute__((address_space(1))) void*)gb,
            (__attribute__((address_space(3))) void*)(Bbuf + p), 16, 0, 0);
    }
}

template <int MODE, int K>
__global__ __launch_bounds__(256) void gemm_kernel(
    const _Float16* __restrict__ A, const _Float16* __restrict__ B,
    _Float16* __restrict__ C, const float* __restrict__ e0,
    const float* __restrict__ e1)
{
    constexpr int KT = K / 64;
    __shared__ f16x8 Abuf[1024];   // 128 rows x 64 cols fp16 = 16 KB
    __shared__ f16x8 Bbuf[1024];

    int t    = threadIdx.x;
    int lane = t & 63, w = t >> 6;
    int wr   = w >> 1, wc = w & 1;
    int lrow = lane & 15, kq = lane >> 4;

    // XCD-aware bijective swizzle: grid = MB*8 (divisible by 8)
    int bid  = blockIdx.x;
    int MBv  = (int)(gridDim.x >> 3);        // number of 128-row m-panels
    int lbid = (bid & 7) * MBv + (bid >> 3);
    int bm   = lbid >> 3, bn = lbid & 7;
    int rowA0 = bm * 128, rowB0 = bn * 128;

    f32x4 acc[4][4];
#pragma unroll
    for (int i = 0; i < 4; ++i)
#pragma unroll
        for (int j = 0; j < 4; ++j) acc[i][j] = (f32x4){0.f, 0.f, 0.f, 0.f};

    stage_pair(A, B, rowA0, rowB0, 0, K, t, Abuf, Bbuf);
    __syncthreads();

    for (int kt = 0; kt < KT; ++kt) {
#pragma unroll
        for (int ks = 0; ks < 2; ++ks) {
            int c   = ks * 4 + kq;
            int swz = c ^ (lrow & 7);
            f16x8 af[4], bf[4];
#pragma unroll
            for (int mi = 0; mi < 4; ++mi)
                af[mi] = Abuf[(wr * 64 + mi * 16 + lrow) * 8 + swz];
#pragma unroll
            for (int ni = 0; ni < 4; ++ni)
                bf[ni] = Bbuf[(wc * 64 + ni * 16 + lrow) * 8 + swz];
#pragma unroll
            for (int mi = 0; mi < 4; ++mi)
#pragma unroll
                for (int ni = 0; ni < 4; ++ni)
                    acc[mi][ni] = __builtin_amdgcn_mfma_f32_16x16x32_f16(
                        af[mi], bf[ni], acc[mi][ni], 0, 0, 0);
        }
        if (kt + 1 < KT) {
            __syncthreads();
            stage_pair(A, B, rowA0, rowB0, (kt + 1) * 64, K, t, Abuf, Bbuf);
            __syncthreads();
        }
    }

    // epilogue
    int gr0 = rowA0 + wr * 64;
    int gc0 = rowB0 + wc * 64;
    float ecol[4];
#pragma unroll
    for (int ni = 0; ni < 4; ++ni)
        ecol[ni] = (MODE == 0) ? e1[gc0 + ni * 16 + lrow]
                               : e0[gc0 + ni * 16 + lrow];
#pragma unroll
    for (int mi = 0; mi < 4; ++mi) {
#pragma unroll
        for (int j = 0; j < 4; ++j) {
            int row = gr0 + mi * 16 + kq * 4 + j;
            float xr = (MODE == 0) ? e0[row] : 0.f;
            size_t base = (size_t)row * 1024 + gc0 + lrow;
#pragma unroll
            for (int ni = 0; ni < 4; ++ni) {
                float v = acc[mi][ni][j];
                if (MODE == 0) {
                    v = __expf(-GAMMA_F * (xr + ecol[ni] - 2.f * v));
                } else {
                    v += ecol[ni];
                    v = fmaxf(v, 0.f);
                }
                C[base + (size_t)ni * 16] = (_Float16)v;
            }
        }
    }
}

// ---------------------------------------------------------------------------
// head: out[b][o] = sum_s h2[b][s]*Wh[o][s] + bh[o], o in {0,1}
// one wave per row, fp16 h2 loads vectorized 16B
// ---------------------------------------------------------------------------
__global__ __launch_bounds__(256) void head_kernel(
    const _Float16* __restrict__ h2, const float* __restrict__ Wh,
    const float* __restrict__ bh, float* __restrict__ out)
{
    int lane = threadIdx.x & 63, w = threadIdx.x >> 6;
    int row = blockIdx.x * 4 + w;
    const _Float16* hp = h2 + (size_t)row * 1024;
    float s0 = 0.f, s1 = 0.f;
#pragma unroll
    for (int i = 0; i < 2; ++i) {
        int base = (i * 64 + lane) * 8;
        f16x8 hv = *(const f16x8*)(hp + base);
#pragma unroll
        for (int j = 0; j < 8; ++j) {
            float hj = (float)hv[j];
            s0 = fmaf(hj, Wh[base + j], s0);
            s1 = fmaf(hj, Wh[1024 + base + j], s1);
        }
    }
#pragma unroll
    for (int off = 32; off; off >>= 1) {
        s0 += __shfl_down(s0, off);
        s1 += __shfl_down(s1, off);
    }
    if (lane == 0) {
        out[(size_t)row * 2 + 0] = s0 + bh[0];
        out[(size_t)row * 2 + 1] = s1 + bh[1];
    }
}

// ---------------------------------------------------------------------------
extern "C" void kernel_launch(void* const* d_in, const int* in_sizes, int n_in,
                              void* d_out, int out_size, void* d_ws, size_t ws_size,
                              hipStream_t stream)
{
    const float* x  = (const float*)d_in[0];   // 65536 x 256
    const float* sv = (const float*)d_in[1];   // 1024 x 256
    const float* W1 = (const float*)d_in[2];   // 1024 x 1024
    const float* b1 = (const float*)d_in[3];   // 1024
    const float* W2 = (const float*)d_in[4];   // 1024 x 1024
    const float* b2 = (const float*)d_in[5];   // 1024
    const float* Wh = (const float*)d_in[6];   // 2 x 1024
    const float* bh = (const float*)d_in[7];   // 2
    float* out = (float*)d_out;
    char* ws = (char*)d_ws;

    // ---- persistent region (~4.6 MB) ----
    constexpr size_t OFF_SV = 0;                        // 512 KB  sv fp16
    constexpr size_t OFF_W1 = OFF_SV + 524288;          // 2 MB    W1 fp16
    constexpr size_t OFF_W2 = OFF_W1 + 2097152;         // 2 MB    W2 fp16
    constexpr size_t OFF_S2 = OFF_W2 + 2097152;         // 4 KB    s2
    constexpr size_t PERSIST = OFF_S2 + 4096;           // = 4722688

    _Float16* svf = (_Float16*)(ws + OFF_SV);
    _Float16* w1f = (_Float16*)(ws + OFF_W1);
    _Float16* w2f = (_Float16*)(ws + OFF_W2);
    float*    s2v = (float*)(ws + OFF_S2);

    // ---- adaptive batch chunking to fit ws_size ----
    // per-chunk: k (Bc*2048) + h1 (Bc*2048, xf overlapped in its head) + x2 (Bc*4)
    int Bc = 65536;
    while (Bc > 128 && PERSIST + (size_t)Bc * 4100ULL > ws_size) Bc >>= 1;

    char* chunk_base = ws + PERSIST;
    _Float16* kb  = (_Float16*)chunk_base;                          // Bc x 1024 fp16
    _Float16* h1b = (_Float16*)(chunk_base + (size_t)Bc * 2048);    // Bc x 1024 fp16
    _Float16* xf  = h1b;                                            // Bc x 256 fp16 (dies before h1 written)
    float*    x2v = (float*)(chunk_base + (size_t)Bc * 4096);       // Bc floats

    // one-time weight/sv prep
    prep_rows_kernel<<<1024 / 4, 256, 0, stream>>>(sv, svf, s2v, 1024);
    cvt_kernel<<<1024, 256, 0, stream>>>(W1, w1f, 262144);
    cvt_kernel<<<1024, 256, 0, stream>>>(W2, w2f, 262144);

    int nchunks = 65536 / Bc;
    int ggrid   = (Bc / 128) * 8;
    for (int c = 0; c < nchunks; ++c) {
        const float* xc = x + (size_t)c * Bc * 256;
        // x fp16 + row norms for this chunk
        prep_rows_kernel<<<Bc / 4, 256, 0, stream>>>(xc, xf, x2v, Bc);
        // k = exp(-g*(x2 + s2 - 2*x.sv))      (Bc x 1024)
        gemm_kernel<0, 256><<<ggrid, 256, 0, stream>>>(xf, svf, kb, x2v, s2v);
        // h1 = relu(k @ W1^T + b1)            (overwrites xf region)
        gemm_kernel<1, 1024><<<ggrid, 256, 0, stream>>>(kb, w1f, h1b, b1, nullptr);
        // h2 = relu(h1 @ W2^T + b2)           (overwrites k buffer)
        gemm_kernel<1, 1024><<<ggrid, 256, 0, stream>>>(h1b, w2f, kb, b2, nullptr);
        // logits for this chunk
        head_kernel<<<Bc / 4, 256, 0, stream>>>(kb, Wh, bh, out + (size_t)c * Bc * 2);
    }
}

// Round 3
// 405.376 us; speedup vs baseline: 1.0311x; 1.0311x over previous
//
#include <hip/hip_runtime.h>

typedef _Float16 f16x8 __attribute__((ext_vector_type(8)));
typedef _Float16 f16x4 __attribute__((ext_vector_type(4)));
typedef float    f32x4 __attribute__((ext_vector_type(4)));

#define GAMMA_F 0.00390625f

// ---------------------------------------------------------------------------
// prep: fp32 -> fp16 row conversion + row sum-of-squares (for x and sv)
// ---------------------------------------------------------------------------
__global__ __launch_bounds__(256) void prep_rows_kernel(
    const float* __restrict__ src, _Float16* __restrict__ dst,
    float* __restrict__ sq, int nrows)
{
    int lane = threadIdx.x & 63, w = threadIdx.x >> 6;
    int row = blockIdx.x * 4 + w;
    if (row >= nrows) return;
    float4 v = ((const float4*)(src + (size_t)row * 256))[lane];
    f16x4 h;
    h[0] = (_Float16)v.x; h[1] = (_Float16)v.y;
    h[2] = (_Float16)v.z; h[3] = (_Float16)v.w;
    *((f16x4*)(dst + (size_t)row * 256) + lane) = h;
    float ss = v.x*v.x + v.y*v.y + v.z*v.z + v.w*v.w;
#pragma unroll
    for (int off = 32; off; off >>= 1) ss += __shfl_down(ss, off);
    if (lane == 0) sq[row] = ss;
}

__global__ __launch_bounds__(256) void cvt_kernel(
    const float* __restrict__ src, _Float16* __restrict__ dst, int n4)
{
    int i = blockIdx.x * 256 + threadIdx.x;
    if (i < n4) {
        float4 v = ((const float4*)src)[i];
        f16x4 h;
        h[0] = (_Float16)v.x; h[1] = (_Float16)v.y;
        h[2] = (_Float16)v.z; h[3] = (_Float16)v.w;
        ((f16x4*)dst)[i] = h;
    }
}

// ---------------------------------------------------------------------------
// 256x256-tile 8-phase GEMM: C[m][n] = epi( sum_k A[m][k]*B[n][k] )
// 8 waves (2M x 4N), BK=64, 2 K-tiles per iteration, dbuf LDS 128 KiB,
// counted vmcnt(4) at phases 4/8, setprio around MFMA clusters,
// st-16x32-style XOR swizzle (pre-swizzled global src, swizzled ds_read).
//   MODE 0: C = exp(-g*(e0[m] + e1[n] - 2*acc))
//   MODE 1: C = relu(acc + e0[n])
// ---------------------------------------------------------------------------
#define SBAR()  __builtin_amdgcn_s_barrier()
#define LGKM0() do { asm volatile("s_waitcnt lgkmcnt(0)" ::: "memory"); \
                     __builtin_amdgcn_sched_barrier(0); } while (0)

#define STAGE(gbase, ldsbase, half, kt) do {                                   \
    const _Float16* _g = (gbase) + (size_t)(half) * (128 * K) + (kt) * 64;     \
    __builtin_amdgcn_global_load_lds(                                          \
        (const __attribute__((address_space(1))) void*)_g,                     \
        (__attribute__((address_space(3))) void*)&lds[(ldsbase) + (half)*1024 + t],       \
        16, 0, 0);                                                             \
    __builtin_amdgcn_global_load_lds(                                          \
        (const __attribute__((address_space(1))) void*)(_g + (size_t)64 * K),  \
        (__attribute__((address_space(3))) void*)&lds[(ldsbase) + (half)*1024 + 512 + t], \
        16, 0, 0);                                                             \
} while (0)

#define READ_A(s, mh) do {                                                     \
    _Pragma("unroll") for (int ks = 0; ks < 2; ++ks)                           \
    _Pragma("unroll") for (int mi = 0; mi < 4; ++mi)                           \
        afr[ks][mi] = lds[(s)*2048 +                                           \
            (wr*128 + (mh)*64 + mi*16 + lrow)*8 + ((ks*4+kq) ^ (lrow&7))];     \
} while (0)

#define READ_B(s, nh) do {                                                     \
    _Pragma("unroll") for (int ks = 0; ks < 2; ++ks)                           \
    _Pragma("unroll") for (int nb = 0; nb < 2; ++nb)                           \
        bfr[ks][(nh)*2+nb] = lds[4096 + (s)*2048 +                             \
            (wc*64 + (nh)*32 + nb*16 + lrow)*8 + ((ks*4+kq) ^ (lrow&7))];      \
} while (0)

#define MFMA16(mh, nh) do {                                                    \
    __builtin_amdgcn_s_setprio(1);                                             \
    _Pragma("unroll") for (int mi = 0; mi < 4; ++mi)                           \
    _Pragma("unroll") for (int nb = 0; nb < 2; ++nb)                           \
    _Pragma("unroll") for (int ks = 0; ks < 2; ++ks)                           \
        acc[(mh)*4+mi][(nh)*2+nb] = __builtin_amdgcn_mfma_f32_16x16x32_f16(    \
            afr[ks][mi], bfr[ks][(nh)*2+nb], acc[(mh)*4+mi][(nh)*2+nb], 0,0,0);\
    __builtin_amdgcn_s_setprio(0);                                             \
} while (0)

template <int MODE, int K>
__global__ __launch_bounds__(512, 2) void gemm256_kernel(
    const _Float16* __restrict__ A, const _Float16* __restrict__ B,
    _Float16* __restrict__ C, const float* __restrict__ e0,
    const float* __restrict__ e1)
{
    constexpr int KT = K / 64;
    constexpr int NITER = KT / 2;
    __shared__ f16x8 lds[8192];   // A: [0,4096) = 2 slots x 256r x 8c ; B: [4096,8192)

    const int t    = threadIdx.x;
    const int lane = t & 63, w = t >> 6;
    const int wr   = w >> 2, wc = w & 3;          // 2 x 4 wave grid
    const int lrow = lane & 15, kq = lane >> 4;

    // XCD-aware bijective swizzle (grid % 8 == 0 by construction)
    int bid  = blockIdx.x;
    int cpx  = (int)(gridDim.x >> 3);
    int lbid = (bid & 7) * cpx + (bid >> 3);
    int bm   = lbid >> 2, bn = lbid & 3;          // NB = 1024/256 = 4
    int rowA0 = bm * 256, rowB0 = bn * 256;

    // per-thread staging base (pre-swizzled global source; row&7 == prow&7)
    const int prow = t >> 3;                      // 0..63 (second load adds 64 rows)
    const int cg   = (t & 7) ^ (prow & 7);
    const _Float16* aSB = A + (size_t)(rowA0 + prow) * K + cg * 8;
    const _Float16* bSB = B + (size_t)(rowB0 + prow) * K + cg * 8;

    f32x4 acc[8][4];
#pragma unroll
    for (int i = 0; i < 8; ++i)
#pragma unroll
        for (int j = 0; j < 4; ++j) acc[i][j] = (f32x4){0.f, 0.f, 0.f, 0.f};

    f16x8 afr[2][4], bfr[2][4];

    // ---- prologue: T0 -> slot0, T1 -> slot1 (16 loads/thread) ----
    STAGE(aSB, 0,    0, 0); STAGE(aSB, 0,    1, 0);
    STAGE(bSB, 4096, 0, 0); STAGE(bSB, 4096, 1, 0);
    STAGE(aSB, 2048, 0, 1); STAGE(aSB, 2048, 1, 1);
    STAGE(bSB, 6144, 0, 1); STAGE(bSB, 6144, 1, 1);
    asm volatile("s_waitcnt vmcnt(8)" ::: "memory");   // T0 landed, T1 in flight
    SBAR();

    for (int j = 0; j < NITER; ++j) {
        const bool last = (j == NITER - 1);
        const int tA = 2 * j + 1;      // this iteration's odd tile (A staged ph1/2)
        const int tN = 2 * j + 2;      // next even tile
        const int tO = 2 * j + 3;      // next odd tile

        // ---- phase 1: tile 2j (slot0), quadrant (m0,n0) ----
        READ_A(0, 0); READ_B(0, 0);
        if (j > 0) STAGE(aSB, 2048, 0, tA);            // (2j+1)-A0 -> s1
        SBAR(); LGKM0();
        MFMA16(0, 0);
        SBAR();
        // ---- phase 2: (m0,n1) ----
        READ_B(0, 1);
        if (j > 0) STAGE(aSB, 2048, 1, tA);            // (2j+1)-A1
        SBAR(); LGKM0();
        MFMA16(0, 1);
        SBAR();
        // ---- phase 3: (m1,n0) ----
        READ_A(0, 1);
        if (!last) STAGE(bSB, 4096, 0, tN);            // (2j+2)-B0 -> s0
        SBAR(); LGKM0();
        MFMA16(1, 0);
        SBAR();
        // ---- phase 4: (m1,n1) + counted vmcnt ----
        if (!last) {
            STAGE(bSB, 4096, 1, tN);                   // (2j+2)-B1
            asm volatile("s_waitcnt vmcnt(4)" ::: "memory");
        } else {
            asm volatile("s_waitcnt vmcnt(0)" ::: "memory");
        }
        SBAR(); LGKM0();
        MFMA16(1, 1);
        SBAR();
        // ---- phase 5: tile 2j+1 (slot1), (m0,n0) ----
        READ_A(1, 0); READ_B(1, 0);
        if (!last) STAGE(aSB, 0, 0, tN);               // (2j+2)-A0 -> s0
        SBAR(); LGKM0();
        MFMA16(0, 0);
        SBAR();
        // ---- phase 6: (m0,n1) ----
        READ_B(1, 1);
        if (!last) STAGE(aSB, 0, 1, tN);               // (2j+2)-A1
        SBAR(); LGKM0();
        MFMA16(0, 1);
        SBAR();
        // ---- phase 7: (m1,n0) ----
        READ_A(1, 1);
        if (!last) STAGE(bSB, 6144, 0, tO);            // (2j+3)-B0 -> s1
        SBAR(); LGKM0();
        MFMA16(1, 0);
        SBAR();
        // ---- phase 8: (m1,n1) + counted vmcnt ----
        if (!last) {
            STAGE(bSB, 6144, 1, tO);                   // (2j+3)-B1
            asm volatile("s_waitcnt vmcnt(4)" ::: "memory");
        }
        SBAR(); LGKM0();
        MFMA16(1, 1);
        SBAR();
    }

    // ---- epilogue ----
    int gr0 = rowA0 + wr * 128;
    int gc0 = rowB0 + wc * 64;
    float ecol[4];
#pragma unroll
    for (int ni = 0; ni < 4; ++ni)
        ecol[ni] = (MODE == 0) ? e1[gc0 + ni * 16 + lrow]
                               : e0[gc0 + ni * 16 + lrow];
#pragma unroll
    for (int mi = 0; mi < 8; ++mi) {
#pragma unroll
        for (int jj = 0; jj < 4; ++jj) {
            int row = gr0 + mi * 16 + kq * 4 + jj;
            float xr = (MODE == 0) ? e0[row] : 0.f;
            size_t base = (size_t)row * 1024 + gc0 + lrow;
#pragma unroll
            for (int ni = 0; ni < 4; ++ni) {
                float v = acc[mi][ni][jj];
                if (MODE == 0) {
                    v = __expf(-GAMMA_F * (xr + ecol[ni] - 2.f * v));
                } else {
                    v += ecol[ni];
                    v = fmaxf(v, 0.f);
                }
                C[base + (size_t)ni * 16] = (_Float16)v;
            }
        }
    }
}

// ---------------------------------------------------------------------------
// head: out[b][o] = sum_s h2[b][s]*Wh[o][s] + bh[o], o in {0,1}
// ---------------------------------------------------------------------------
__global__ __launch_bounds__(256) void head_kernel(
    const _Float16* __restrict__ h2, const float* __restrict__ Wh,
    const float* __restrict__ bh, float* __restrict__ out)
{
    int lane = threadIdx.x & 63, w = threadIdx.x >> 6;
    int row = blockIdx.x * 4 + w;
    const _Float16* hp = h2 + (size_t)row * 1024;
    float s0 = 0.f, s1 = 0.f;
#pragma unroll
    for (int i = 0; i < 2; ++i) {
        int base = (i * 64 + lane) * 8;
        f16x8 hv = *(const f16x8*)(hp + base);
#pragma unroll
        for (int j = 0; j < 8; ++j) {
            float hj = (float)hv[j];
            s0 = fmaf(hj, Wh[base + j], s0);
            s1 = fmaf(hj, Wh[1024 + base + j], s1);
        }
    }
#pragma unroll
    for (int off = 32; off; off >>= 1) {
        s0 += __shfl_down(s0, off);
        s1 += __shfl_down(s1, off);
    }
    if (lane == 0) {
        out[(size_t)row * 2 + 0] = s0 + bh[0];
        out[(size_t)row * 2 + 1] = s1 + bh[1];
    }
}

// ---------------------------------------------------------------------------
extern "C" void kernel_launch(void* const* d_in, const int* in_sizes, int n_in,
                              void* d_out, int out_size, void* d_ws, size_t ws_size,
                              hipStream_t stream)
{
    const float* x  = (const float*)d_in[0];
    const float* sv = (const float*)d_in[1];
    const float* W1 = (const float*)d_in[2];
    const float* b1 = (const float*)d_in[3];
    const float* W2 = (const float*)d_in[4];
    const float* b2 = (const float*)d_in[5];
    const float* Wh = (const float*)d_in[6];
    const float* bh = (const float*)d_in[7];
    float* out = (float*)d_out;
    char* ws = (char*)d_ws;

    // ---- persistent region (~4.6 MB) ----
    constexpr size_t OFF_SV = 0;
    constexpr size_t OFF_W1 = OFF_SV + 524288;
    constexpr size_t OFF_W2 = OFF_W1 + 2097152;
    constexpr size_t OFF_S2 = OFF_W2 + 2097152;
    constexpr size_t PERSIST = OFF_S2 + 4096;

    _Float16* svf = (_Float16*)(ws + OFF_SV);
    _Float16* w1f = (_Float16*)(ws + OFF_W1);
    _Float16* w2f = (_Float16*)(ws + OFF_W2);
    float*    s2v = (float*)(ws + OFF_S2);

    // ---- adaptive batch chunking ----
    int Bc = 65536;
    while (Bc > 256 && PERSIST + (size_t)Bc * 4100ULL > ws_size) Bc >>= 1;

    char* chunk_base = ws + PERSIST;
    _Float16* kb  = (_Float16*)chunk_base;                        // Bc x 1024 fp16
    _Float16* h1b = (_Float16*)(chunk_base + (size_t)Bc * 2048);  // Bc x 1024 fp16
    _Float16* xf  = h1b;                                          // overlapped (dies before h1 written)
    float*    x2v = (float*)(chunk_base + (size_t)Bc * 4096);

    prep_rows_kernel<<<1024 / 4, 256, 0, stream>>>(sv, svf, s2v, 1024);
    cvt_kernel<<<1024, 256, 0, stream>>>(W1, w1f, 262144);
    cvt_kernel<<<1024, 256, 0, stream>>>(W2, w2f, 262144);

    int nchunks = 65536 / Bc;
    int ggrid   = (Bc / 256) * 4;
    for (int c = 0; c < nchunks; ++c) {
        const float* xc = x + (size_t)c * Bc * 256;
        prep_rows_kernel<<<Bc / 4, 256, 0, stream>>>(xc, xf, x2v, Bc);
        gemm256_kernel<0, 256><<<ggrid, 512, 0, stream>>>(xf, svf, kb, x2v, s2v);
        gemm256_kernel<1, 1024><<<ggrid, 512, 0, stream>>>(kb, w1f, h1b, b1, nullptr);
        gemm256_kernel<1, 1024><<<ggrid, 512, 0, stream>>>(h1b, w2f, kb, b2, nullptr);
        head_kernel<<<Bc / 4, 256, 0, stream>>>(kb, Wh, bh, out + (size_t)c * Bc * 2);
    }
}